// Round 4
// baseline (1063.196 us; speedup 1.0000x reference)
//
#include <hip/hip_runtime.h>

typedef unsigned short u16;
typedef __attribute__((ext_vector_type(8))) short short8;
typedef __attribute__((ext_vector_type(4))) float f32x4;

#define SCALE_QK 0.17677669529663687f
#define LOG2E 1.44269504088896f

__device__ __forceinline__ u16 f2b(float f) {
  union { float f; unsigned int i; } v; v.f = f;
  unsigned int x = v.i;
  x += 0x7fffu + ((x >> 16) & 1u);   // round-to-nearest-even
  return (u16)(x >> 16);
}
__device__ __forceinline__ float lo16(unsigned int u) {
  union { unsigned int i; float f; } v; v.i = u << 16; return v.f;
}
__device__ __forceinline__ float hi16(unsigned int u) {
  union { unsigned int i; float f; } v; v.i = u & 0xffff0000u; return v.f;
}
// async global->LDS, 16B per lane; LDS dst = wave-uniform base + lane*16
__device__ __forceinline__ void gll16(const void* g, void* l) {
  __builtin_amdgcn_global_load_lds(
      (const __attribute__((address_space(1))) unsigned int*)g,
      (__attribute__((address_space(3))) unsigned int*)l, 16, 0, 0);
}

// token index -> element offset into XR, laid out as (B=4,S=512,F=32,D=256)
__device__ __forceinline__ size_t map_off(int m, int map) {
  if (map == 0) return ((size_t)m) << 8;
  int r, s;
  if (map == 1) { r = m / 384; s = m - r * 384; }
  else          { r = m >> 7;  s = 384 + (m & 127); }
  int b = r >> 5, f = r & 31;
  return ((size_t)((b * 512 + s) * 32 + f)) << 8;
}

// ---------------------------------------------------------------- mask decode
__global__ void decode_mask_kernel(const int* __restrict__ mraw,
                                   float* __restrict__ bias) {
  __shared__ int isbyte;
  if (threadIdx.x == 0) isbyte = 0;
  __syncthreads();
  for (int i = threadIdx.x; i < 1024; i += 256) {
    unsigned int v = (unsigned int)mraw[i];
    if (v > 1u) atomicOr(&isbyte, 1);
  }
  __syncthreads();
  bool byt = (isbyte != 0);
  const unsigned char* mb = (const unsigned char*)mraw;
  for (int i = threadIdx.x; i < 4096; i += 256) {
    bool on = byt ? (mb[i] != 0) : (mraw[i] != 0);
    bias[i] = on ? 0.f : -1e30f;
  }
}

// ---------------------------------------------------------------- weight cvt
struct WPtrs { const float* p[15]; };
__global__ __launch_bounds__(256) void cvt_w_kernel(WPtrs wp, u16* __restrict__ out) {
  int gid = blockIdx.x * 256 + threadIdx.x;
  int e0 = gid * 8;
  if (e0 >= 1572864) return;
  int mi, off;
  if (e0 < 786432) { mi = e0 >> 16; off = e0 & 65535; }
  else { int j = e0 - 786432; mi = 12 + (j >> 18); off = j & 262143; }
  const float* s = wp.p[mi] + off;
  float4 a = *(const float4*)s;
  float4 b = *(const float4*)(s + 4);
  union { u16 u[8]; uint4 v; } pk;
  pk.u[0] = f2b(a.x); pk.u[1] = f2b(a.y); pk.u[2] = f2b(a.z); pk.u[3] = f2b(a.w);
  pk.u[4] = f2b(b.x); pk.u[5] = f2b(b.y); pk.u[6] = f2b(b.z); pk.u[7] = f2b(b.w);
  *(uint4*)(out + e0) = pk.v;
}

// ---------------------------------------------------------------- layernorm
__global__ __launch_bounds__(256) void ln_kernel(
    const float* __restrict__ src, float* __restrict__ cpy,
    u16* __restrict__ dst, const float* __restrict__ g,
    const float* __restrict__ bt, int M, int map) {
  int widx = blockIdx.x * 4 + (threadIdx.x >> 6);
  if (widx >= M) return;
  int lane = threadIdx.x & 63;
  size_t off = map_off(widx, map);
  float4 xv = ((const float4*)(src + off))[lane];
  float s = xv.x + xv.y + xv.z + xv.w;
#pragma unroll
  for (int o = 32; o; o >>= 1) s += __shfl_xor(s, o);
  float mean = s * (1.f / 256.f);
  float dx = xv.x - mean, dy = xv.y - mean, dz = xv.z - mean, dw = xv.w - mean;
  float ss = dx * dx + dy * dy + dz * dz + dw * dw;
#pragma unroll
  for (int o = 32; o; o >>= 1) ss += __shfl_xor(ss, o);
  float rs = rsqrtf(ss * (1.f / 256.f) + 1e-5f);
  float4 gv = ((const float4*)g)[lane];
  float4 bv = ((const float4*)bt)[lane];
  ushort4 st;
  st.x = f2b(dx * rs * gv.x + bv.x);
  st.y = f2b(dy * rs * gv.y + bv.y);
  st.z = f2b(dz * rs * gv.z + bv.z);
  st.w = f2b(dw * rs * gv.w + bv.w);
  *(ushort4*)(dst + ((size_t)widx << 8) + lane * 4) = st;
  if (cpy) ((float4*)(cpy + off))[lane] = xv;
}

// ---------------------------------------------------------------- GEMM 128x128 (m97 structure)
// C[M,N] = A[M,K](bf16) * W[N,K](bf16)^T + bias
// mode 0: bf16 to outB; mode 1/2/3: XR[map_off(row,mode-1)+col] += v
__global__ __launch_bounds__(256, 2) void gemm_nt(
    const u16* __restrict__ A, const u16* __restrict__ W,
    const float* __restrict__ bias, u16* __restrict__ outB,
    float* __restrict__ outF, int M, int N, int K, int mode) {
  __shared__ u16 As[128 * 64];
  __shared__ u16 Bs[128 * 64];
  int tid = threadIdx.x, lane = tid & 63, w = tid >> 6;
  int wr = w >> 1, wc = w & 1;
  int m0 = blockIdx.x * 128, n0 = blockIdx.y * 128;
  int fr = lane & 15, fg = lane >> 4;
  f32x4 z = {0.f, 0.f, 0.f, 0.f};
  f32x4 acc[4][4];
#pragma unroll
  for (int i = 0; i < 4; ++i)
#pragma unroll
    for (int j = 0; j < 4; ++j) acc[i][j] = z;
  int r8 = lane >> 3, seg = lane & 7;
  const u16* gA = A + (size_t)(m0 + w * 32 + r8) * K + seg * 8;
  const u16* gB = W + (size_t)(n0 + w * 32 + r8) * K + seg * 8;
  u16* lA = As + (w * 32) * 64;
  u16* lB = Bs + (w * 32) * 64;
  for (int kt = 0; kt < K; kt += 64) {
#pragma unroll
    for (int j = 0; j < 4; ++j) {
      gll16(gA + (size_t)(j * 8) * K + kt, lA + j * 512);
      gll16(gB + (size_t)(j * 8) * K + kt, lB + j * 512);
    }
    __syncthreads();
#pragma unroll
    for (int ks = 0; ks < 2; ++ks) {
      short8 af[4], bf[4];
#pragma unroll
      for (int i = 0; i < 4; ++i) {
        af[i] = *(const short8*)(As + (wr * 64 + i * 16 + fr) * 64 + ks * 32 + fg * 8);
        bf[i] = *(const short8*)(Bs + (wc * 64 + i * 16 + fr) * 64 + ks * 32 + fg * 8);
      }
#pragma unroll
      for (int mi = 0; mi < 4; ++mi)
#pragma unroll
        for (int ni = 0; ni < 4; ++ni)
          acc[mi][ni] = __builtin_amdgcn_mfma_f32_16x16x32_bf16(af[mi], bf[ni], acc[mi][ni], 0, 0, 0);
    }
    __syncthreads();
  }
#pragma unroll
  for (int mi = 0; mi < 4; ++mi)
#pragma unroll
    for (int ni = 0; ni < 4; ++ni) {
      int col = n0 + wc * 64 + ni * 16 + fr;
      float bv = bias ? bias[col] : 0.f;
#pragma unroll
      for (int r = 0; r < 4; ++r) {
        int row = m0 + wr * 64 + mi * 16 + fg * 4 + r;
        float v = acc[mi][ni][r] + bv;
        if (mode == 0) {
          outB[(size_t)row * N + col] = f2b(v);
        } else {
          outF[map_off(row, mode - 1) + col] += v;
        }
      }
    }
}

// ---------------------------------------------------------------- dual GEMM 128x128 (MLP up+gate)
// Hb[M,1024] = (A*W1^T + b1) * silu(A*Wg^T + bg)
__global__ __launch_bounds__(256, 2) void gemm_dual(
    const u16* __restrict__ A, const u16* __restrict__ W1,
    const float* __restrict__ b1, const u16* __restrict__ Wg,
    const float* __restrict__ bg, u16* __restrict__ Hb,
    int M, int N, int K) {
  __shared__ u16 As[128 * 64];
  __shared__ u16 W1s[128 * 64];
  __shared__ u16 Wgs[128 * 64];
  int tid = threadIdx.x, lane = tid & 63, w = tid >> 6;
  int wr = w >> 1, wc = w & 1;
  int m0 = blockIdx.x * 128, n0 = blockIdx.y * 128;
  int fr = lane & 15, fg = lane >> 4;
  f32x4 z = {0.f, 0.f, 0.f, 0.f};
  f32x4 ac1[4][4], ac2[4][4];
#pragma unroll
  for (int i = 0; i < 4; ++i)
#pragma unroll
    for (int j = 0; j < 4; ++j) { ac1[i][j] = z; ac2[i][j] = z; }
  int r8 = lane >> 3, seg = lane & 7;
  const u16* gA = A + (size_t)(m0 + w * 32 + r8) * K + seg * 8;
  const u16* g1 = W1 + (size_t)(n0 + w * 32 + r8) * K + seg * 8;
  const u16* g2 = Wg + (size_t)(n0 + w * 32 + r8) * K + seg * 8;
  u16* lA = As + (w * 32) * 64;
  u16* l1 = W1s + (w * 32) * 64;
  u16* l2 = Wgs + (w * 32) * 64;
  for (int kt = 0; kt < K; kt += 64) {
#pragma unroll
    for (int j = 0; j < 4; ++j) {
      gll16(gA + (size_t)(j * 8) * K + kt, lA + j * 512);
      gll16(g1 + (size_t)(j * 8) * K + kt, l1 + j * 512);
      gll16(g2 + (size_t)(j * 8) * K + kt, l2 + j * 512);
    }
    __syncthreads();
#pragma unroll
    for (int ks = 0; ks < 2; ++ks) {
      short8 af[4], bf1[4], bf2[4];
#pragma unroll
      for (int i = 0; i < 4; ++i) {
        af[i]  = *(const short8*)(As  + (wr * 64 + i * 16 + fr) * 64 + ks * 32 + fg * 8);
        bf1[i] = *(const short8*)(W1s + (wc * 64 + i * 16 + fr) * 64 + ks * 32 + fg * 8);
        bf2[i] = *(const short8*)(Wgs + (wc * 64 + i * 16 + fr) * 64 + ks * 32 + fg * 8);
      }
#pragma unroll
      for (int mi = 0; mi < 4; ++mi)
#pragma unroll
        for (int ni = 0; ni < 4; ++ni) {
          ac1[mi][ni] = __builtin_amdgcn_mfma_f32_16x16x32_bf16(af[mi], bf1[ni], ac1[mi][ni], 0, 0, 0);
          ac2[mi][ni] = __builtin_amdgcn_mfma_f32_16x16x32_bf16(af[mi], bf2[ni], ac2[mi][ni], 0, 0, 0);
        }
    }
    __syncthreads();
  }
#pragma unroll
  for (int mi = 0; mi < 4; ++mi)
#pragma unroll
    for (int ni = 0; ni < 4; ++ni) {
      int col = n0 + wc * 64 + ni * 16 + fr;
      float bb1 = b1[col], bbg = bg[col];
#pragma unroll
      for (int r = 0; r < 4; ++r) {
        int row = m0 + wr * 64 + mi * 16 + fg * 4 + r;
        float v1 = ac1[mi][ni][r] + bb1;
        float v2 = ac2[mi][ni][r] + bbg;
        float sg = v2 / (1.f + __expf(-v2));
        Hb[(size_t)row * N + col] = f2b(v1 * sg);
      }
    }
}

// ---------------------------------------------------------------- feature attention
__global__ __launch_bounds__(256) void fa_kernel(
    const u16* __restrict__ Q, const u16* __restrict__ K,
    const u16* __restrict__ V, u16* __restrict__ CTX,
    const float* __restrict__ bias) {
  __shared__ u16 Ks[8192];     // [h*32+tok][32]
  __shared__ u16 Vs[8192];
  __shared__ float Bs[1056];   // [q][33] padded
  int tid = threadIdx.x;
  int row = blockIdx.x;
  size_t base = (size_t)row << 13;
#pragma unroll
  for (int it = 0; it < 4; ++it) {
    int c = it * 256 + tid;
    int tok = c >> 5, d8 = c & 31;
    int dst = ((d8 >> 2) * 32 + tok) * 32 + (d8 & 3) * 8;
    *(uint4*)&Ks[dst] = *(const uint4*)(K + base + tok * 256 + d8 * 8);
    *(uint4*)&Vs[dst] = *(const uint4*)(V + base + tok * 256 + d8 * 8);
  }
  {
    const float* bp = bias + (size_t)(row >> 9) * 1024;
#pragma unroll
    for (int it = 0; it < 4; ++it) {
      int i = it * 256 + tid;
      Bs[(i >> 5) * 33 + (i & 31)] = bp[i];
    }
  }
  __syncthreads();
  int h = tid >> 5, q = tid & 31;
  float qr[32];
  {
    const u16* qp = Q + base + q * 256 + h * 32;
    const float sc = SCALE_QK * LOG2E;
#pragma unroll
    for (int j = 0; j < 4; ++j) {
      uint4 u = ((const uint4*)qp)[j];
      qr[j * 8 + 0] = lo16(u.x) * sc; qr[j * 8 + 1] = hi16(u.x) * sc;
      qr[j * 8 + 2] = lo16(u.y) * sc; qr[j * 8 + 3] = hi16(u.y) * sc;
      qr[j * 8 + 4] = lo16(u.z) * sc; qr[j * 8 + 5] = hi16(u.z) * sc;
      qr[j * 8 + 6] = lo16(u.w) * sc; qr[j * 8 + 7] = hi16(u.w) * sc;
    }
  }
  float s[32], m = -3e38f;
  const u16* kb = Ks + h * 1024;
  const float* brow = Bs + q * 33;
#pragma unroll 4
  for (int k = 0; k < 32; ++k) {
    const uint4* kr = (const uint4*)(kb + k * 32);
    float d0 = 0.f, d1 = 0.f, d2 = 0.f, d3 = 0.f;
#pragma unroll
    for (int j = 0; j < 4; ++j) {
      uint4 u = kr[j];
      d0 += qr[j * 8 + 0] * lo16(u.x); d1 += qr[j * 8 + 1] * hi16(u.x);
      d2 += qr[j * 8 + 2] * lo16(u.y); d3 += qr[j * 8 + 3] * hi16(u.y);
      d0 += qr[j * 8 + 4] * lo16(u.z); d1 += qr[j * 8 + 5] * hi16(u.z);
      d2 += qr[j * 8 + 6] * lo16(u.w); d3 += qr[j * 8 + 7] * hi16(u.w);
    }
    float sv = (d0 + d1) + (d2 + d3) + brow[k];
    s[k] = sv;
    m = fmaxf(m, sv);
  }
  float l = 0.f;
#pragma unroll
  for (int k = 0; k < 32; ++k) {
    float p = exp2f(s[k] - m);
    s[k] = p; l += p;
  }
  float inv = 1.f / l;
  float out[32];
#pragma unroll
  for (int d = 0; d < 32; ++d) out[d] = 0.f;
  const u16* vb = Vs + h * 1024;
#pragma unroll 4
  for (int k = 0; k < 32; ++k) {
    float wgt = s[k];
    const uint4* vr = (const uint4*)(vb + k * 32);
#pragma unroll
    for (int j = 0; j < 4; ++j) {
      uint4 u = vr[j];
      out[j * 8 + 0] += wgt * lo16(u.x); out[j * 8 + 1] += wgt * hi16(u.x);
      out[j * 8 + 2] += wgt * lo16(u.y); out[j * 8 + 3] += wgt * hi16(u.y);
      out[j * 8 + 4] += wgt * lo16(u.z); out[j * 8 + 5] += wgt * hi16(u.z);
      out[j * 8 + 6] += wgt * lo16(u.w); out[j * 8 + 7] += wgt * hi16(u.w);
    }
  }
  u16* op = CTX + base + q * 256 + h * 32;
#pragma unroll
  for (int j = 0; j < 4; ++j) {
    union { u16 u[8]; uint4 v; } pk;
#pragma unroll
    for (int e = 0; e < 8; ++e) pk.u[e] = f2b(out[j * 8 + e] * inv);
    ((uint4*)op)[j] = pk.v;
  }
}

// ---------------------------------------------------------------- sample attention (MFMA)
__global__ __launch_bounds__(256) void sa_mfma_kernel(
    const u16* __restrict__ Q, const u16* __restrict__ K,
    const u16* __restrict__ V, u16* __restrict__ CTX, int Lq) {
  __shared__ u16 Ks[384 * 40];
  __shared__ u16 Vt[32 * 392];
  __shared__ u16 Pb[4][16 * 72];
  int tid = threadIdx.x, lane = tid & 63, w = tid >> 6;
  int rh = blockIdx.x;
  int row = rh >> 3, h = rh & 7;
  size_t kvb = ((size_t)row * 384) * 256 + h * 32;
  for (int c = tid; c < 1536; c += 256) {
    int k = c >> 2, seg = c & 3;
    uint4 kk = *(const uint4*)(K + kvb + (size_t)k * 256 + seg * 8);
    *(uint4*)&Ks[k * 40 + seg * 8] = kk;
    uint4 vv = *(const uint4*)(V + kvb + (size_t)k * 256 + seg * 8);
    union { u16 u[8]; uint4 v; } t; t.v = vv;
#pragma unroll
    for (int j = 0; j < 8; ++j) Vt[(seg * 8 + j) * 392 + k] = t.u[j];
  }
  __syncthreads();
  int fr = lane & 15, fg = lane >> 4;
  const float sc = SCALE_QK * LOG2E;
  int nqt = Lq >> 4;
  f32x4 zz = {0.f, 0.f, 0.f, 0.f};
  for (int qt = w; qt < nqt; qt += 4) {
    int q0 = qt << 4;
    short8 a_q = *(const short8*)(Q + ((size_t)row * Lq + q0 + fr) * 256 + h * 32 + fg * 8);
    f32x4 O0 = zz, O1 = zz;
    float m[4] = {-3e38f, -3e38f, -3e38f, -3e38f};
    float l[4] = {0.f, 0.f, 0.f, 0.f};
    u16* pb = Pb[w];
    for (int c0 = 0; c0 < 384; c0 += 64) {
      f32x4 s[4];
#pragma unroll
      for (int kt = 0; kt < 4; ++kt) {
        short8 b_k = *(const short8*)(Ks + (c0 + kt * 16 + fr) * 40 + fg * 8);
        s[kt] = __builtin_amdgcn_mfma_f32_16x16x32_bf16(a_q, b_k, zz, 0, 0, 0);
      }
      float rm[4];
#pragma unroll
      for (int r = 0; r < 4; ++r)
        rm[r] = fmaxf(fmaxf(s[0][r], s[1][r]), fmaxf(s[2][r], s[3][r]));
#pragma unroll
      for (int o = 1; o <= 8; o <<= 1)
#pragma unroll
        for (int r = 0; r < 4; ++r) rm[r] = fmaxf(rm[r], __shfl_xor(rm[r], o));
      float al[4];
#pragma unroll
      for (int r = 0; r < 4; ++r) {
        float mn = fmaxf(m[r], rm[r] * sc);
        al[r] = exp2f(m[r] - mn);
        m[r] = mn;
        l[r] *= al[r];
        O0[r] *= al[r];
        O1[r] *= al[r];
      }
#pragma unroll
      for (int kt = 0; kt < 4; ++kt)
#pragma unroll
        for (int r = 0; r < 4; ++r) {
          float p = exp2f(fmaf(s[kt][r], sc, -m[r]));
          l[r] += p;
          pb[(fg * 4 + r) * 72 + kt * 16 + fr] = f2b(p);
        }
      asm volatile("s_waitcnt lgkmcnt(0)" ::: "memory");
      __builtin_amdgcn_wave_barrier();
#pragma unroll
      for (int sub = 0; sub < 2; ++sub) {
        short8 a_p = *(const short8*)(pb + fr * 72 + sub * 32 + fg * 8);
        short8 b_v0 = *(const short8*)(Vt + fr * 392 + c0 + sub * 32 + fg * 8);
        short8 b_v1 = *(const short8*)(Vt + (16 + fr) * 392 + c0 + sub * 32 + fg * 8);
        O0 = __builtin_amdgcn_mfma_f32_16x16x32_bf16(a_p, b_v0, O0, 0, 0, 0);
        O1 = __builtin_amdgcn_mfma_f32_16x16x32_bf16(a_p, b_v1, O1, 0, 0, 0);
      }
      __builtin_amdgcn_wave_barrier();
    }
#pragma unroll
    for (int o = 1; o <= 8; o <<= 1)
#pragma unroll
      for (int r = 0; r < 4; ++r) l[r] += __shfl_xor(l[r], o);
    u16* op = CTX + ((size_t)row * Lq + q0) * 256 + h * 32;
#pragma unroll
    for (int r = 0; r < 4; ++r) {
      float inv = 1.f / l[r];
      int orow = fg * 4 + r;
      op[orow * 256 + fr] = f2b(O0[r] * inv);
      op[orow * 256 + 16 + fr] = f2b(O1[r] * inv);
    }
  }
}

// ---------------------------------------------------------------- launch
extern "C" void kernel_launch(void* const* d_in, const int* in_sizes, int n_in,
                              void* d_out, int out_size, void* d_ws, size_t ws_size,
                              hipStream_t stream) {
  const float* x    = (const float*)d_in[0];
  const int*   mask = (const int*)d_in[1];
  const float* bq_f = (const float*)d_in[8],  *bk_f = (const float*)d_in[9];
  const float* bv_f = (const float*)d_in[10], *bo_f = (const float*)d_in[11];
  const float* bq_t = (const float*)d_in[16], *bk_t = (const float*)d_in[17];
  const float* bv_t = (const float*)d_in[18], *bo_t = (const float*)d_in[19];
  const float* bq_s = (const float*)d_in[24], *bk_s = (const float*)d_in[25];
  const float* bv_s = (const float*)d_in[26], *bo_s = (const float*)d_in[27];
  const float* g_f = (const float*)d_in[28], *b_f = (const float*)d_in[29];
  const float* g_t = (const float*)d_in[30], *b_t = (const float*)d_in[31];
  const float* g_s = (const float*)d_in[32], *b_s = (const float*)d_in[33];
  const float* g_m = (const float*)d_in[34], *b_m = (const float*)d_in[35];
  const float* b1 = (const float*)d_in[37];
  const float* bg = (const float*)d_in[39];
  const float* b2 = (const float*)d_in[41];

  float* XR = (float*)d_out;                 // residual stream, (B,S,F,D) fp32
  char* ws = (char*)d_ws;
  float* BIAS = (float*)ws;                  // 16 KB
  u16* XN = (u16*)(ws + 16384);
  u16* QB = XN + 16777216;
  u16* KB = QB + 16777216;
  u16* VB = KB + 16777216;
  u16* XM = VB + 16777216;
  u16* WB = XM + 16777216;                   // bf16 weights, 1572864 elems
  u16* HB = XN;                              // MLP hidden reuses XN..VB span

  WPtrs wp;
  wp.p[0] = (const float*)d_in[4];  wp.p[1] = (const float*)d_in[5];
  wp.p[2] = (const float*)d_in[6];  wp.p[3] = (const float*)d_in[7];
  wp.p[4] = (const float*)d_in[12]; wp.p[5] = (const float*)d_in[13];
  wp.p[6] = (const float*)d_in[14]; wp.p[7] = (const float*)d_in[15];
  wp.p[8] = (const float*)d_in[20]; wp.p[9] = (const float*)d_in[21];
  wp.p[10] = (const float*)d_in[22]; wp.p[11] = (const float*)d_in[23];
  wp.p[12] = (const float*)d_in[36]; wp.p[13] = (const float*)d_in[38];
  wp.p[14] = (const float*)d_in[40];
  const u16 *WQF = WB, *WKF = WB + 65536, *WVF = WB + 131072, *WOF = WB + 196608;
  const u16 *WQT = WB + 262144, *WKT = WB + 327680, *WVT = WB + 393216, *WOT = WB + 458752;
  const u16 *WQS = WB + 524288, *WKS = WB + 589824, *WVS = WB + 655360, *WOS = WB + 720896;
  const u16 *W1B = WB + 786432, *WGB = WB + 1048576, *W2B = WB + 1310720;

  cvt_w_kernel<<<768, 256, 0, stream>>>(wp, WB);
  decode_mask_kernel<<<1, 256, 0, stream>>>(mask, BIAS);

  // ---- feature stage (rows = B*S = 2048, F=32 tokens) ----
  ln_kernel<<<16384, 256, 0, stream>>>(x, XR, XN, g_f, b_f, 65536, 0);
  gemm_nt<<<dim3(512, 2), 256, 0, stream>>>(XN, WQF, bq_f, QB, nullptr, 65536, 256, 256, 0);
  gemm_nt<<<dim3(512, 2), 256, 0, stream>>>(XN, WKF, bk_f, KB, nullptr, 65536, 256, 256, 0);
  gemm_nt<<<dim3(512, 2), 256, 0, stream>>>(XN, WVF, bv_f, VB, nullptr, 65536, 256, 256, 0);
  fa_kernel<<<2048, 256, 0, stream>>>(QB, KB, VB, XN, BIAS);
  gemm_nt<<<dim3(512, 2), 256, 0, stream>>>(XN, WOF, bo_f, nullptr, XR, 65536, 256, 256, 1);

  // ---- train self-attention (rows = B*F = 128, 384 tokens) ----
  ln_kernel<<<12288, 256, 0, stream>>>(XR, nullptr, XN, g_t, b_t, 49152, 1);
  gemm_nt<<<dim3(384, 2), 256, 0, stream>>>(XN, WQT, bq_t, QB, nullptr, 49152, 256, 256, 0);
  gemm_nt<<<dim3(384, 2), 256, 0, stream>>>(XN, WKT, bk_t, KB, nullptr, 49152, 256, 256, 0);
  gemm_nt<<<dim3(384, 2), 256, 0, stream>>>(XN, WVT, bv_t, VB, nullptr, 49152, 256, 256, 0);
  sa_mfma_kernel<<<1024, 256, 0, stream>>>(QB, KB, VB, XN, 384);
  gemm_nt<<<dim3(384, 2), 256, 0, stream>>>(XN, WOT, bo_t, nullptr, XR, 49152, 256, 256, 2);

  // ---- test cross-attention (q: 128 tokens, kv: updated train 384 tokens) ----
  ln_kernel<<<4096, 256, 0, stream>>>(XR, nullptr, XN, g_s, b_s, 16384, 2);
  gemm_nt<<<dim3(128, 2), 256, 0, stream>>>(XN, WQS, bq_s, QB, nullptr, 16384, 256, 256, 0);
  ln_kernel<<<12288, 256, 0, stream>>>(XR, nullptr, XN, g_s, b_s, 49152, 1);
  gemm_nt<<<dim3(384, 2), 256, 0, stream>>>(XN, WKS, bk_s, KB, nullptr, 49152, 256, 256, 0);
  gemm_nt<<<dim3(384, 2), 256, 0, stream>>>(XN, WVS, bv_s, VB, nullptr, 49152, 256, 256, 0);
  sa_mfma_kernel<<<1024, 256, 0, stream>>>(QB, KB, VB, XN, 128);
  gemm_nt<<<dim3(128, 2), 256, 0, stream>>>(XN, WOS, bo_s, nullptr, XR, 16384, 256, 256, 3);

  // ---- MLP (gated), out = xc + W2-proj ----
  ln_kernel<<<16384, 256, 0, stream>>>(XR, nullptr, XM, g_m, b_m, 65536, 0);
  gemm_dual<<<dim3(512, 8), 256, 0, stream>>>(XM, W1B, b1, WGB, bg, HB, 65536, 1024, 256);
  gemm_nt<<<dim3(512, 2), 256, 0, stream>>>(HB, W2B, b2, nullptr, XR, 65536, 256, 1024, 1);
}

// Round 5
// 973.053 us; speedup vs baseline: 1.0926x; 1.0926x over previous
//
#include <hip/hip_runtime.h>

typedef unsigned short u16;
typedef __attribute__((ext_vector_type(8))) short short8;
typedef __attribute__((ext_vector_type(4))) float f32x4;

#define SCALE_QK 0.17677669529663687f
#define LOG2E 1.44269504088896f
#define QKV_SPACING 16777216ULL

__device__ __forceinline__ u16 f2b(float f) {
  union { float f; unsigned int i; } v; v.f = f;
  unsigned int x = v.i;
  x += 0x7fffu + ((x >> 16) & 1u);   // round-to-nearest-even
  return (u16)(x >> 16);
}
__device__ __forceinline__ float lo16(unsigned int u) {
  union { unsigned int i; float f; } v; v.i = u << 16; return v.f;
}
__device__ __forceinline__ float hi16(unsigned int u) {
  union { unsigned int i; float f; } v; v.i = u & 0xffff0000u; return v.f;
}
// async global->LDS, 16B per lane; LDS dst = wave-uniform base + lane*16
__device__ __forceinline__ void gll16(const void* g, void* l) {
  __builtin_amdgcn_global_load_lds(
      (const __attribute__((address_space(1))) unsigned int*)g,
      (__attribute__((address_space(3))) unsigned int*)l, 16, 0, 0);
}

// token index -> element offset into XR, laid out as (B=4,S=512,F=32,D=256)
__device__ __forceinline__ size_t map_off(int m, int map) {
  if (map == 0) return ((size_t)m) << 8;
  int r, s;
  if (map == 1) { r = m / 384; s = m - r * 384; }
  else          { r = m >> 7;  s = 384 + (m & 127); }
  int b = r >> 5, f = r & 31;
  return ((size_t)((b * 512 + s) * 32 + f)) << 8;
}

// ---------------------------------------------------------------- mask decode
__global__ void decode_mask_kernel(const int* __restrict__ mraw,
                                   float* __restrict__ bias) {
  __shared__ int isbyte;
  if (threadIdx.x == 0) isbyte = 0;
  __syncthreads();
  for (int i = threadIdx.x; i < 1024; i += 256) {
    unsigned int v = (unsigned int)mraw[i];
    if (v > 1u) atomicOr(&isbyte, 1);
  }
  __syncthreads();
  bool byt = (isbyte != 0);
  const unsigned char* mb = (const unsigned char*)mraw;
  for (int i = threadIdx.x; i < 4096; i += 256) {
    bool on = byt ? (mb[i] != 0) : (mraw[i] != 0);
    bias[i] = on ? 0.f : -1e30f;
  }
}

// ---------------------------------------------------------------- weight cvt
struct WPtrs { const float* p[15]; };
__global__ __launch_bounds__(256) void cvt_w_kernel(WPtrs wp, u16* __restrict__ out) {
  int gid = blockIdx.x * 256 + threadIdx.x;
  int e0 = gid * 8;
  if (e0 >= 1572864) return;
  int mi, off;
  if (e0 < 786432) { mi = e0 >> 16; off = e0 & 65535; }
  else { int j = e0 - 786432; mi = 12 + (j >> 18); off = j & 262143; }
  const float* s = wp.p[mi] + off;
  float4 a = *(const float4*)s;
  float4 b = *(const float4*)(s + 4);
  union { u16 u[8]; uint4 v; } pk;
  pk.u[0] = f2b(a.x); pk.u[1] = f2b(a.y); pk.u[2] = f2b(a.z); pk.u[3] = f2b(a.w);
  pk.u[4] = f2b(b.x); pk.u[5] = f2b(b.y); pk.u[6] = f2b(b.z); pk.u[7] = f2b(b.w);
  *(uint4*)(out + e0) = pk.v;
}

// ---------------------------------------------------------------- layernorm
__global__ __launch_bounds__(256) void ln_kernel(
    const float* __restrict__ src, float* __restrict__ cpy,
    u16* __restrict__ dst, const float* __restrict__ g,
    const float* __restrict__ bt, int M, int map) {
  int widx = blockIdx.x * 4 + (threadIdx.x >> 6);
  if (widx >= M) return;
  int lane = threadIdx.x & 63;
  size_t off = map_off(widx, map);
  float4 xv = ((const float4*)(src + off))[lane];
  float s = xv.x + xv.y + xv.z + xv.w;
#pragma unroll
  for (int o = 32; o; o >>= 1) s += __shfl_xor(s, o);
  float mean = s * (1.f / 256.f);
  float dx = xv.x - mean, dy = xv.y - mean, dz = xv.z - mean, dw = xv.w - mean;
  float ss = dx * dx + dy * dy + dz * dz + dw * dw;
#pragma unroll
  for (int o = 32; o; o >>= 1) ss += __shfl_xor(ss, o);
  float rs = rsqrtf(ss * (1.f / 256.f) + 1e-5f);
  float4 gv = ((const float4*)g)[lane];
  float4 bv = ((const float4*)bt)[lane];
  ushort4 st;
  st.x = f2b(dx * rs * gv.x + bv.x);
  st.y = f2b(dy * rs * gv.y + bv.y);
  st.z = f2b(dz * rs * gv.z + bv.z);
  st.w = f2b(dw * rs * gv.w + bv.w);
  *(ushort4*)(dst + ((size_t)widx << 8) + lane * 4) = st;
  if (cpy) ((float4*)(cpy + off))[lane] = xv;
}

// ---------------------------------------------------------------- GEMM 128x128, swizzled LDS
// C[M,N] = A[M,K](bf16) * W[N,K](bf16)^T + bias(col-block select)
// mode 0: bf16 write, split buffers: outB + (col>>8)*QKV_SPACING + row*256 + (col&255)
// mode 1/2/3: outF[map_off(row,mode-1)+col] += v
// LDS layout: [row][chunk] where chunk c of row r holds global k-chunk c^(r&7).
__global__ __launch_bounds__(256, 2) void gemm_nt(
    const u16* __restrict__ A, const u16* __restrict__ W,
    const float* __restrict__ b0, const float* __restrict__ b1,
    const float* __restrict__ b2, u16* __restrict__ outB,
    float* __restrict__ outF, int M, int N, int K, int mode) {
  __shared__ u16 As[128 * 64];
  __shared__ u16 Bs[128 * 64];
  int tid = threadIdx.x, lane = tid & 63, w = tid >> 6;
  int wr = w >> 1, wc = w & 1;
  int m0 = blockIdx.x * 128, n0 = blockIdx.y * 128;
  int fr = lane & 15, fg = lane >> 4;
  f32x4 z = {0.f, 0.f, 0.f, 0.f};
  f32x4 acc[4][4];
#pragma unroll
  for (int i = 0; i < 4; ++i)
#pragma unroll
    for (int j = 0; j < 4; ++j) acc[i][j] = z;
  int r8 = lane >> 3, seg = lane & 7;
  // lane fetches k-chunk seg^r8 so LDS chunk 'seg' holds k-chunk seg^(row&7)
  const u16* gA = A + (size_t)(m0 + w * 32 + r8) * K + (seg ^ r8) * 8;
  const u16* gB = W + (size_t)(n0 + w * 32 + r8) * K + (seg ^ r8) * 8;
  u16* lA = As + (w * 32) * 64;
  u16* lB = Bs + (w * 32) * 64;
  for (int kt = 0; kt < K; kt += 64) {
#pragma unroll
    for (int j = 0; j < 4; ++j) {
      gll16(gA + (size_t)(j * 8) * K + kt, lA + j * 512);
      gll16(gB + (size_t)(j * 8) * K + kt, lB + j * 512);
    }
    __syncthreads();
#pragma unroll
    for (int ks = 0; ks < 2; ++ks) {
      short8 af[4], bf[4];
#pragma unroll
      for (int i = 0; i < 4; ++i) {
        int ra = wr * 64 + i * 16 + fr;
        int rb = wc * 64 + i * 16 + fr;
        int sw = ((ks * 4 + fg) ^ (fr & 7)) * 8;
        af[i] = *(const short8*)(As + ra * 64 + sw);
        bf[i] = *(const short8*)(Bs + rb * 64 + sw);
      }
#pragma unroll
      for (int mi = 0; mi < 4; ++mi)
#pragma unroll
        for (int ni = 0; ni < 4; ++ni)
          acc[mi][ni] = __builtin_amdgcn_mfma_f32_16x16x32_bf16(af[mi], bf[ni], acc[mi][ni], 0, 0, 0);
    }
    __syncthreads();
  }
#pragma unroll
  for (int mi = 0; mi < 4; ++mi)
#pragma unroll
    for (int ni = 0; ni < 4; ++ni) {
      int col = n0 + wc * 64 + ni * 16 + fr;
      int bsel = col >> 8;
      const float* bp = bsel == 0 ? b0 : (bsel == 1 ? b1 : b2);
      float bv = bp ? bp[col & 255] : 0.f;
#pragma unroll
      for (int r = 0; r < 4; ++r) {
        int row = m0 + wr * 64 + mi * 16 + fg * 4 + r;
        float v = acc[mi][ni][r] + bv;
        if (mode == 0) {
          outB[(size_t)bsel * QKV_SPACING + (size_t)row * 256 + (col & 255)] = f2b(v);
        } else {
          outF[map_off(row, mode - 1) + col] += v;
        }
      }
    }
}

// ---------------------------------------------------------------- dual GEMM 128x128 (MLP up+gate)
__global__ __launch_bounds__(256, 2) void gemm_dual(
    const u16* __restrict__ A, const u16* __restrict__ W1,
    const float* __restrict__ b1, const u16* __restrict__ Wg,
    const float* __restrict__ bg, u16* __restrict__ Hb,
    int M, int N, int K) {
  __shared__ u16 As[128 * 64];
  __shared__ u16 W1s[128 * 64];
  __shared__ u16 Wgs[128 * 64];
  int tid = threadIdx.x, lane = tid & 63, w = tid >> 6;
  int wr = w >> 1, wc = w & 1;
  int m0 = blockIdx.x * 128, n0 = blockIdx.y * 128;
  int fr = lane & 15, fg = lane >> 4;
  f32x4 z = {0.f, 0.f, 0.f, 0.f};
  f32x4 ac1[4][4], ac2[4][4];
#pragma unroll
  for (int i = 0; i < 4; ++i)
#pragma unroll
    for (int j = 0; j < 4; ++j) { ac1[i][j] = z; ac2[i][j] = z; }
  int r8 = lane >> 3, seg = lane & 7;
  const u16* gA = A + (size_t)(m0 + w * 32 + r8) * K + (seg ^ r8) * 8;
  const u16* g1 = W1 + (size_t)(n0 + w * 32 + r8) * K + (seg ^ r8) * 8;
  const u16* g2 = Wg + (size_t)(n0 + w * 32 + r8) * K + (seg ^ r8) * 8;
  u16* lA = As + (w * 32) * 64;
  u16* l1 = W1s + (w * 32) * 64;
  u16* l2 = Wgs + (w * 32) * 64;
  for (int kt = 0; kt < K; kt += 64) {
#pragma unroll
    for (int j = 0; j < 4; ++j) {
      gll16(gA + (size_t)(j * 8) * K + kt, lA + j * 512);
      gll16(g1 + (size_t)(j * 8) * K + kt, l1 + j * 512);
      gll16(g2 + (size_t)(j * 8) * K + kt, l2 + j * 512);
    }
    __syncthreads();
#pragma unroll
    for (int ks = 0; ks < 2; ++ks) {
      short8 af[4], bf1[4], bf2[4];
#pragma unroll
      for (int i = 0; i < 4; ++i) {
        int ra = wr * 64 + i * 16 + fr;
        int rb = wc * 64 + i * 16 + fr;
        int sw = ((ks * 4 + fg) ^ (fr & 7)) * 8;
        af[i]  = *(const short8*)(As  + ra * 64 + sw);
        bf1[i] = *(const short8*)(W1s + rb * 64 + sw);
        bf2[i] = *(const short8*)(Wgs + rb * 64 + sw);
      }
#pragma unroll
      for (int mi = 0; mi < 4; ++mi)
#pragma unroll
        for (int ni = 0; ni < 4; ++ni) {
          ac1[mi][ni] = __builtin_amdgcn_mfma_f32_16x16x32_bf16(af[mi], bf1[ni], ac1[mi][ni], 0, 0, 0);
          ac2[mi][ni] = __builtin_amdgcn_mfma_f32_16x16x32_bf16(af[mi], bf2[ni], ac2[mi][ni], 0, 0, 0);
        }
    }
    __syncthreads();
  }
#pragma unroll
  for (int mi = 0; mi < 4; ++mi)
#pragma unroll
    for (int ni = 0; ni < 4; ++ni) {
      int col = n0 + wc * 64 + ni * 16 + fr;
      float bb1 = b1[col], bbg = bg[col];
#pragma unroll
      for (int r = 0; r < 4; ++r) {
        int row = m0 + wr * 64 + mi * 16 + fg * 4 + r;
        float v1 = ac1[mi][ni][r] + bb1;
        float v2 = ac2[mi][ni][r] + bbg;
        float sg = v2 / (1.f + __expf(-v2));
        Hb[(size_t)row * N + col] = f2b(v1 * sg);
      }
    }
}

// ---------------------------------------------------------------- feature attention
__global__ __launch_bounds__(256) void fa_kernel(
    const u16* __restrict__ Q, const u16* __restrict__ K,
    const u16* __restrict__ V, u16* __restrict__ CTX,
    const float* __restrict__ bias) {
  __shared__ u16 Ks[8192];     // [h*32+tok][32]
  __shared__ u16 Vs[8192];
  __shared__ float Bs[1056];   // [q][33] padded
  int tid = threadIdx.x;
  int row = blockIdx.x;
  size_t base = (size_t)row << 13;
#pragma unroll
  for (int it = 0; it < 4; ++it) {
    int c = it * 256 + tid;
    int tok = c >> 5, d8 = c & 31;
    int dst = ((d8 >> 2) * 32 + tok) * 32 + (d8 & 3) * 8;
    *(uint4*)&Ks[dst] = *(const uint4*)(K + base + tok * 256 + d8 * 8);
    *(uint4*)&Vs[dst] = *(const uint4*)(V + base + tok * 256 + d8 * 8);
  }
  {
    const float* bp = bias + (size_t)(row >> 9) * 1024;
#pragma unroll
    for (int it = 0; it < 4; ++it) {
      int i = it * 256 + tid;
      Bs[(i >> 5) * 33 + (i & 31)] = bp[i];
    }
  }
  __syncthreads();
  int h = tid >> 5, q = tid & 31;
  float qr[32];
  {
    const u16* qp = Q + base + q * 256 + h * 32;
    const float sc = SCALE_QK * LOG2E;
#pragma unroll
    for (int j = 0; j < 4; ++j) {
      uint4 u = ((const uint4*)qp)[j];
      qr[j * 8 + 0] = lo16(u.x) * sc; qr[j * 8 + 1] = hi16(u.x) * sc;
      qr[j * 8 + 2] = lo16(u.y) * sc; qr[j * 8 + 3] = hi16(u.y) * sc;
      qr[j * 8 + 4] = lo16(u.z) * sc; qr[j * 8 + 5] = hi16(u.z) * sc;
      qr[j * 8 + 6] = lo16(u.w) * sc; qr[j * 8 + 7] = hi16(u.w) * sc;
    }
  }
  float s[32], m = -3e38f;
  const u16* kb = Ks + h * 1024;
  const float* brow = Bs + q * 33;
#pragma unroll 4
  for (int k = 0; k < 32; ++k) {
    const uint4* kr = (const uint4*)(kb + k * 32);
    float d0 = 0.f, d1 = 0.f, d2 = 0.f, d3 = 0.f;
#pragma unroll
    for (int j = 0; j < 4; ++j) {
      uint4 u = kr[j];
      d0 += qr[j * 8 + 0] * lo16(u.x); d1 += qr[j * 8 + 1] * hi16(u.x);
      d2 += qr[j * 8 + 2] * lo16(u.y); d3 += qr[j * 8 + 3] * hi16(u.y);
      d0 += qr[j * 8 + 4] * lo16(u.z); d1 += qr[j * 8 + 5] * hi16(u.z);
      d2 += qr[j * 8 + 6] * lo16(u.w); d3 += qr[j * 8 + 7] * hi16(u.w);
    }
    float sv = (d0 + d1) + (d2 + d3) + brow[k];
    s[k] = sv;
    m = fmaxf(m, sv);
  }
  float l = 0.f;
#pragma unroll
  for (int k = 0; k < 32; ++k) {
    float p = exp2f(s[k] - m);
    s[k] = p; l += p;
  }
  float inv = 1.f / l;
  float out[32];
#pragma unroll
  for (int d = 0; d < 32; ++d) out[d] = 0.f;
  const u16* vb = Vs + h * 1024;
#pragma unroll 4
  for (int k = 0; k < 32; ++k) {
    float wgt = s[k];
    const uint4* vr = (const uint4*)(vb + k * 32);
#pragma unroll
    for (int j = 0; j < 4; ++j) {
      uint4 u = vr[j];
      out[j * 8 + 0] += wgt * lo16(u.x); out[j * 8 + 1] += wgt * hi16(u.x);
      out[j * 8 + 2] += wgt * lo16(u.y); out[j * 8 + 3] += wgt * hi16(u.y);
      out[j * 8 + 4] += wgt * lo16(u.z); out[j * 8 + 5] += wgt * hi16(u.z);
      out[j * 8 + 6] += wgt * lo16(u.w); out[j * 8 + 7] += wgt * hi16(u.w);
    }
  }
  u16* op = CTX + base + q * 256 + h * 32;
#pragma unroll
  for (int j = 0; j < 4; ++j) {
    union { u16 u[8]; uint4 v; } pk;
#pragma unroll
    for (int e = 0; e < 8; ++e) pk.u[e] = f2b(out[j * 8 + e] * inv);
    ((uint4*)op)[j] = pk.v;
  }
}

// ---------------------------------------------------------------- sample attention (MFMA)
__global__ __launch_bounds__(256) void sa_mfma_kernel(
    const u16* __restrict__ Q, const u16* __restrict__ K,
    const u16* __restrict__ V, u16* __restrict__ CTX, int Lq) {
  __shared__ u16 Ks[384 * 40];
  __shared__ u16 Vt[32 * 392];
  __shared__ u16 Pb[4][16 * 72];
  int tid = threadIdx.x, lane = tid & 63, w = tid >> 6;
  int rh = blockIdx.x;
  int row = rh >> 3, h = rh & 7;
  size_t kvb = ((size_t)row * 384) * 256 + h * 32;
  for (int c = tid; c < 1536; c += 256) {
    int k = c >> 2, seg = c & 3;
    uint4 kk = *(const uint4*)(K + kvb + (size_t)k * 256 + seg * 8);
    *(uint4*)&Ks[k * 40 + seg * 8] = kk;
    uint4 vv = *(const uint4*)(V + kvb + (size_t)k * 256 + seg * 8);
    union { u16 u[8]; uint4 v; } t; t.v = vv;
#pragma unroll
    for (int j = 0; j < 8; ++j) Vt[(seg * 8 + j) * 392 + k] = t.u[j];
  }
  __syncthreads();
  int fr = lane & 15, fg = lane >> 4;
  const float sc = SCALE_QK * LOG2E;
  int nqt = Lq >> 4;
  f32x4 zz = {0.f, 0.f, 0.f, 0.f};
  for (int qt = w; qt < nqt; qt += 4) {
    int q0 = qt << 4;
    short8 a_q = *(const short8*)(Q + ((size_t)row * Lq + q0 + fr) * 256 + h * 32 + fg * 8);
    f32x4 O0 = zz, O1 = zz;
    float m[4] = {-3e38f, -3e38f, -3e38f, -3e38f};
    float l[4] = {0.f, 0.f, 0.f, 0.f};
    u16* pb = Pb[w];
    for (int c0 = 0; c0 < 384; c0 += 64) {
      f32x4 s[4];
#pragma unroll
      for (int kt = 0; kt < 4; ++kt) {
        short8 b_k = *(const short8*)(Ks + (c0 + kt * 16 + fr) * 40 + fg * 8);
        s[kt] = __builtin_amdgcn_mfma_f32_16x16x32_bf16(a_q, b_k, zz, 0, 0, 0);
      }
      float rm[4];
#pragma unroll
      for (int r = 0; r < 4; ++r)
        rm[r] = fmaxf(fmaxf(s[0][r], s[1][r]), fmaxf(s[2][r], s[3][r]));
#pragma unroll
      for (int o = 1; o <= 8; o <<= 1)
#pragma unroll
        for (int r = 0; r < 4; ++r) rm[r] = fmaxf(rm[r], __shfl_xor(rm[r], o));
      float al[4];
#pragma unroll
      for (int r = 0; r < 4; ++r) {
        float mn = fmaxf(m[r], rm[r] * sc);
        al[r] = exp2f(m[r] - mn);
        m[r] = mn;
        l[r] *= al[r];
        O0[r] *= al[r];
        O1[r] *= al[r];
      }
#pragma unroll
      for (int kt = 0; kt < 4; ++kt)
#pragma unroll
        for (int r = 0; r < 4; ++r) {
          float p = exp2f(fmaf(s[kt][r], sc, -m[r]));
          l[r] += p;
          pb[(fg * 4 + r) * 72 + kt * 16 + fr] = f2b(p);
        }
      asm volatile("s_waitcnt lgkmcnt(0)" ::: "memory");
      __builtin_amdgcn_wave_barrier();
#pragma unroll
      for (int sub = 0; sub < 2; ++sub) {
        short8 a_p = *(const short8*)(pb + fr * 72 + sub * 32 + fg * 8);
        short8 b_v0 = *(const short8*)(Vt + fr * 392 + c0 + sub * 32 + fg * 8);
        short8 b_v1 = *(const short8*)(Vt + (16 + fr) * 392 + c0 + sub * 32 + fg * 8);
        O0 = __builtin_amdgcn_mfma_f32_16x16x32_bf16(a_p, b_v0, O0, 0, 0, 0);
        O1 = __builtin_amdgcn_mfma_f32_16x16x32_bf16(a_p, b_v1, O1, 0, 0, 0);
      }
      __builtin_amdgcn_wave_barrier();
    }
#pragma unroll
    for (int o = 1; o <= 8; o <<= 1)
#pragma unroll
      for (int r = 0; r < 4; ++r) l[r] += __shfl_xor(l[r], o);
    u16* op = CTX + ((size_t)row * Lq + q0) * 256 + h * 32;
#pragma unroll
    for (int r = 0; r < 4; ++r) {
      float inv = 1.f / l[r];
      int orow = fg * 4 + r;
      op[orow * 256 + fr] = f2b(O0[r] * inv);
      op[orow * 256 + 16 + fr] = f2b(O1[r] * inv);
    }
  }
}

// ---------------------------------------------------------------- launch
extern "C" void kernel_launch(void* const* d_in, const int* in_sizes, int n_in,
                              void* d_out, int out_size, void* d_ws, size_t ws_size,
                              hipStream_t stream) {
  const float* x    = (const float*)d_in[0];
  const int*   mask = (const int*)d_in[1];
  const float* bq_f = (const float*)d_in[8],  *bk_f = (const float*)d_in[9];
  const float* bv_f = (const float*)d_in[10], *bo_f = (const float*)d_in[11];
  const float* bq_t = (const float*)d_in[16], *bk_t = (const float*)d_in[17];
  const float* bv_t = (const float*)d_in[18], *bo_t = (const float*)d_in[19];
  const float* bq_s = (const float*)d_in[24], *bk_s = (const float*)d_in[25];
  const float* bv_s = (const float*)d_in[26], *bo_s = (const float*)d_in[27];
  const float* g_f = (const float*)d_in[28], *b_f = (const float*)d_in[29];
  const float* g_t = (const float*)d_in[30], *b_t = (const float*)d_in[31];
  const float* g_s = (const float*)d_in[32], *b_s = (const float*)d_in[33];
  const float* g_m = (const float*)d_in[34], *b_m = (const float*)d_in[35];
  const float* b1 = (const float*)d_in[37];
  const float* bg = (const float*)d_in[39];
  const float* b2 = (const float*)d_in[41];

  float* XR = (float*)d_out;                 // residual stream, (B,S,F,D) fp32
  char* ws = (char*)d_ws;
  float* BIAS = (float*)ws;                  // 16 KB
  u16* XN = (u16*)(ws + 16384);
  u16* QB = XN + 16777216;                   // QB/KB/VB spaced QKV_SPACING
  u16* KB = QB + 16777216;
  u16* VB = KB + 16777216;
  u16* XM = VB + 16777216;
  u16* WB = XM + 16777216;                   // bf16 weights, 1572864 elems
  u16* HB = XN;                              // MLP hidden reuses XN..VB span

  WPtrs wp;
  wp.p[0] = (const float*)d_in[4];  wp.p[1] = (const float*)d_in[5];
  wp.p[2] = (const float*)d_in[6];  wp.p[3] = (const float*)d_in[7];
  wp.p[4] = (const float*)d_in[12]; wp.p[5] = (const float*)d_in[13];
  wp.p[6] = (const float*)d_in[14]; wp.p[7] = (const float*)d_in[15];
  wp.p[8] = (const float*)d_in[20]; wp.p[9] = (const float*)d_in[21];
  wp.p[10] = (const float*)d_in[22]; wp.p[11] = (const float*)d_in[23];
  wp.p[12] = (const float*)d_in[36]; wp.p[13] = (const float*)d_in[38];
  wp.p[14] = (const float*)d_in[40];
  // Wq/Wk/Wv contiguous per stage => fused QKV weight is a [768][256] block
  const u16 *WQKV_F = WB;                    // rows 0-767
  const u16 *WOF = WB + 196608;
  const u16 *WQKV_T = WB + 262144;
  const u16 *WOT = WB + 458752;
  const u16 *WQS = WB + 524288;
  const u16 *WKV_S = WB + 589824;            // rows: Wk_s, Wv_s (512 rows)
  const u16 *WOS = WB + 720896;
  const u16 *W1B = WB + 786432, *WGB = WB + 1048576, *W2B = WB + 1310720;

  cvt_w_kernel<<<768, 256, 0, stream>>>(wp, WB);
  decode_mask_kernel<<<1, 256, 0, stream>>>(mask, BIAS);

  // ---- feature stage (rows = B*S = 2048, F=32 tokens) ----
  ln_kernel<<<16384, 256, 0, stream>>>(x, XR, XN, g_f, b_f, 65536, 0);
  gemm_nt<<<dim3(512, 6), 256, 0, stream>>>(XN, WQKV_F, bq_f, bk_f, bv_f, QB, nullptr, 65536, 768, 256, 0);
  fa_kernel<<<2048, 256, 0, stream>>>(QB, KB, VB, XN, BIAS);
  gemm_nt<<<dim3(512, 2), 256, 0, stream>>>(XN, WOF, bo_f, nullptr, nullptr, nullptr, XR, 65536, 256, 256, 1);

  // ---- train self-attention (rows = B*F = 128, 384 tokens) ----
  ln_kernel<<<12288, 256, 0, stream>>>(XR, nullptr, XN, g_t, b_t, 49152, 1);
  gemm_nt<<<dim3(384, 6), 256, 0, stream>>>(XN, WQKV_T, bq_t, bk_t, bv_t, QB, nullptr, 49152, 768, 256, 0);
  sa_mfma_kernel<<<1024, 256, 0, stream>>>(QB, KB, VB, XN, 384);
  gemm_nt<<<dim3(384, 2), 256, 0, stream>>>(XN, WOT, bo_t, nullptr, nullptr, nullptr, XR, 49152, 256, 256, 2);

  // ---- test cross-attention (q: 128 tokens, kv: updated train 384 tokens) ----
  ln_kernel<<<4096, 256, 0, stream>>>(XR, nullptr, XN, g_s, b_s, 16384, 2);
  gemm_nt<<<dim3(128, 2), 256, 0, stream>>>(XN, WQS, bq_s, nullptr, nullptr, QB, nullptr, 16384, 256, 256, 0);
  ln_kernel<<<12288, 256, 0, stream>>>(XR, nullptr, XN, g_s, b_s, 49152, 1);
  gemm_nt<<<dim3(384, 4), 256, 0, stream>>>(XN, WKV_S, bk_s, bv_s, nullptr, KB, nullptr, 49152, 512, 256, 0);
  sa_mfma_kernel<<<1024, 256, 0, stream>>>(QB, KB, VB, XN, 128);
  gemm_nt<<<dim3(128, 2), 256, 0, stream>>>(XN, WOS, bo_s, nullptr, nullptr, nullptr, XR, 16384, 256, 256, 3);

  // ---- MLP (gated), out = xc + W2-proj ----
  ln_kernel<<<16384, 256, 0, stream>>>(XR, nullptr, XM, g_m, b_m, 65536, 0);
  gemm_dual<<<dim3(512, 8), 256, 0, stream>>>(XM, W1B, b1, WGB, bg, HB, 65536, 1024, 256);
  gemm_nt<<<dim3(512, 2), 256, 0, stream>>>(HB, W2B, b2, nullptr, nullptr, nullptr, XR, 65536, 256, 1024, 1);
}